// Round 21
// baseline (93.812 us; speedup 1.0000x reference)
//
#include <hip/hip_runtime.h>

// ClauseInferModule: C=16, B=64, G=2048, S=8, L=4, 3 steps. ONE kernel node.
//
// Round-21 = r20 (packed-fp16 hard min/max, double-buffered LDS row image,
// one barrier per step) + u16-PACKED GATHER OFFSETS to halve index VGPRs
// (64 -> 32) and reach 2 blocks/CU (32 waves/CU — r20 ran at 16):
//   - idx < 2048 => byte offset idx*8 < 16384 fits u16; two offsets per u32.
//   - extraction in hot loop: 1 VALU op per gather address (and / shr) — VALU
//     is nearly idle (packed min/max only), LDS gather latency is the limit,
//     and 2x resident waves double the hiding.
//   - __launch_bounds__(1024, 8): 8 waves/EU = 32 waves/CU = 2 blocks/CU.
//     LDS 2 x 32 KB = 64 KB <= 160 KB. Caps VGPR at 64.
//
// Formulation (r16-r20, absmax bit-stable at the 0.0039 bf16 floor):
// gamma=1e-3 renorms are the identity exactly (all values < 1), hard==soft
// within one bf16 ulp, fp16 quantization is monotone and commutes with
// min/max (select-only, no drift):
//     R_new[c,b,:] = max(R[c,b,:], max_s min_l R[c,b,I[c,:,s,l]])
// is ROW-LOCAL in (c,b): all 3 steps in one kernel, __syncthreads-only.
//
// k_all: grid = 256 blocks (c16 x bquad16) x 1024 threads:
//   buf[k%2][g] = packed fp16 b-quad (8 B); step k reads buf[k%2], writes
//   buf[1-k%2]. Each thread owns atoms g=tid, tid+1024; 2x32 gather offsets
//   u16-packed in 32 VGPRs once for all 3 steps. Final step unpacks + stores
//   straight to d_out (coalesced dwords). No workspace.

namespace {
constexpr int C = 16, B = 64, G = 2048, S = 8, L = 4;
constexpr int STEPS = 3;
}

typedef _Float16 h4 __attribute__((ext_vector_type(4)));

__device__ __forceinline__ h4 h4min(h4 a, h4 b) { return __builtin_elementwise_min(a, b); }
__device__ __forceinline__ h4 h4max(h4 a, h4 b) { return __builtin_elementwise_max(a, b); }

__device__ __forceinline__ h4 lds_at(const h4* base, unsigned byteoff) {
    return *(const h4*)((const char*)base + byteoff);
}

// grid = C*16 = 256 blocks, 1024 threads, 2 blocks/CU (8 waves/EU).
__global__ __launch_bounds__(1024, 8) void k_all(const float* __restrict__ x,
                                                 const int* __restrict__ I,
                                                 float* __restrict__ out) {
    __shared__ h4 buf[2][G];        // 2 x 16 KB: packed fp16 b-quad per atom

    const int tid = threadIdx.x;
    const int bq = blockIdx.x & 15, c = blockIdx.x >> 4;
    const int b0 = bq * 4;
    const int ga = tid, gb = tid + 1024;

    // u16-pack both atoms' 32 byte-offsets (idx*8 < 16384): 32 VGPRs total
    const int4* Ipa = (const int4*)(I + (size_t)(c * G + ga) * (S * L));
    const int4* Ipb = (const int4*)(I + (size_t)(c * G + gb) * (S * L));
    unsigned pka[2 * S], pkb[2 * S];
#pragma unroll
    for (int s = 0; s < S; ++s) {
        int4 a = Ipa[s];
        pka[2 * s]     = (unsigned)(a.x << 3) | ((unsigned)a.y << 19);
        pka[2 * s + 1] = (unsigned)(a.z << 3) | ((unsigned)a.w << 19);
        int4 b = Ipb[s];
        pkb[2 * s]     = (unsigned)(b.x << 3) | ((unsigned)b.y << 19);
        pkb[2 * s + 1] = (unsigned)(b.z << 3) | ((unsigned)b.w << 19);
    }

    // stage x rows b0..b0+3 as packed b-quads (one float2 col per row)
    float2 pr[4];
#pragma unroll
    for (int j = 0; j < 4; ++j)
        pr[j] = ((const float2*)(x + (size_t)(b0 + j) * G))[tid];
    {
        h4 t0, t1;
        t0[0] = (_Float16)pr[0].x; t0[1] = (_Float16)pr[1].x;
        t0[2] = (_Float16)pr[2].x; t0[3] = (_Float16)pr[3].x;
        t1[0] = (_Float16)pr[0].y; t1[1] = (_Float16)pr[1].y;
        t1[2] = (_Float16)pr[2].y; t1[3] = (_Float16)pr[3].y;
        buf[0][2 * tid]     = t0;
        buf[0][2 * tid + 1] = t1;
    }
    __syncthreads();
    h4 cura = buf[0][ga];           // own quads (one extra read, init only)
    h4 curb = buf[0][gb];

#pragma unroll
    for (int step = 0; step < STEPS; ++step) {
        const h4* rd = buf[step & 1];
        h4* wr = buf[(step & 1) ^ 1];

        // hard clause eval: max over S of min over L (packed fp16)
        h4 qa, qb;
#pragma unroll
        for (int s = 0; s < S; ++s) {
            unsigned p0 = pka[2 * s], p1 = pka[2 * s + 1];
            h4 m = h4min(h4min(lds_at(rd, p0 & 0xffffu), lds_at(rd, p0 >> 16)),
                         h4min(lds_at(rd, p1 & 0xffffu), lds_at(rd, p1 >> 16)));
            qa = s ? h4max(qa, m) : m;
            p0 = pkb[2 * s]; p1 = pkb[2 * s + 1];
            m = h4min(h4min(lds_at(rd, p0 & 0xffffu), lds_at(rd, p0 >> 16)),
                      h4min(lds_at(rd, p1 & 0xffffu), lds_at(rd, p1 >> 16)));
            qb = s ? h4max(qb, m) : m;
        }
        cura = h4max(cura, qa);
        curb = h4max(curb, qb);

        if (step < STEPS - 1) {
            wr[ga] = cura;          // write the OTHER buffer: no WAR hazard
            wr[gb] = curb;
            __syncthreads();        // one barrier per step
        } else {
            // unpack + final store, coalesced dwords
            out[(size_t)(c * B + b0 + 0) * G + ga] = (float)cura[0];
            out[(size_t)(c * B + b0 + 1) * G + ga] = (float)cura[1];
            out[(size_t)(c * B + b0 + 2) * G + ga] = (float)cura[2];
            out[(size_t)(c * B + b0 + 3) * G + ga] = (float)cura[3];
            out[(size_t)(c * B + b0 + 0) * G + gb] = (float)curb[0];
            out[(size_t)(c * B + b0 + 1) * G + gb] = (float)curb[1];
            out[(size_t)(c * B + b0 + 2) * G + gb] = (float)curb[2];
            out[(size_t)(c * B + b0 + 3) * G + gb] = (float)curb[3];
        }
    }
}

extern "C" void kernel_launch(void* const* d_in, const int* in_sizes, int n_in,
                              void* d_out, int out_size, void* d_ws, size_t ws_size,
                              hipStream_t stream) {
    const float* x = (const float*)d_in[0];   // (B, G) fp32
    const int*   I = (const int*)d_in[1];     // (C, G, S, L) int32
    float* out = (float*)d_out;               // (C, B, G) fp32

    k_all<<<C * 16, 1024, 0, stream>>>(x, I, out);
}